// Round 19
// baseline (354.289 us; speedup 1.0000x reference)
//
#include <hip/hip_runtime.h>

typedef __attribute__((ext_vector_type(4))) float f32x4;
typedef __attribute__((ext_vector_type(8))) short s16x8;

#define MFMA16(a, b, c) __builtin_amdgcn_mfma_f32_16x16x32_bf16((a), (b), (c), 0, 0, 0)

__device__ __forceinline__ float hsig(float x) {
    return fminf(fmaxf(0.2f * x + 0.5f, 0.0f), 1.0f);
}

__device__ __forceinline__ unsigned short bf16rne(float v) {
    unsigned u = __float_as_uint(v);
    u += 0x7FFFu + ((u >> 16) & 1u);
    return (unsigned short)(u >> 16);
}

// ---- weight prep: MFMA A-fragment order, GATE-INTERLEAVED rows, bf16 RNE ----
// Bw layout: [ks][ nfrag(16) x lane(64) x 8 ]  (8192 ushorts per ks)
// Row n = output channel in interleaved order c' = 4*feature + gate.
template<int KHW, int CX, int NS>
__global__ __launch_bounds__(256)
void prep_w(const float* __restrict__ Kw, const float* __restrict__ Rw,
            unsigned short* __restrict__ Bw)
{
    int gid = blockIdx.x * 256 + threadIdx.x;
    if (gid >= NS * 1024) return;
    int lane  = gid & 63;
    int nfrag = (gid >> 6) & 15;
    int ks    = gid >> 10;
    int n   = nfrag * 16 + (lane & 15);       // interleaved channel c'
    int src = (n & 3) * 64 + (n >> 2);        // original col: gate*64 + feature
    int kl  = (lane >> 4) * 8;
    constexpr int KX = KHW * CX;
    s16x8 vh;
#pragma unroll
    for (int j = 0; j < 8; ++j) {
        int kg = ks * 32 + kl + j;
        float w = (kg < KX) ? Kw[(long)kg * 256 + src]
                            : Rw[(long)(kg - KX) * 256 + src];
        vh[j] = (short)bf16rne(w);
    }
    unsigned short* o = Bw + (long)ks * 8192 + nfrag * 512 + lane * 8;
    *(s16x8*)o = vh;
}

// ---- stage zero-padded tile as SINGLE bf16 plane (RNE), chunk-major ----
template<int C, int TS, int PAD, int CST>
__device__ __forceinline__ void stage_bf16(const float* __restrict__ gp,
                                           unsigned short* __restrict__ dst,
                                           int ty0, int tx0, int tid)
{
    constexpr int CH = C / 8;
    constexpr int NP = TS * TS;
    for (int i = tid; i < NP * CH; i += 512) {
        int ch = i % CH;
        int p  = i / CH;
        int py = p / TS, px = p % TS;
        int iy = ty0 + py - PAD, ix = tx0 + px - PAD;
        s16x8 vb;
        if (iy >= 0 && iy < 64 && ix >= 0 && ix < 64) {
            const float* s = gp + ((long)(iy * 64 + ix)) * C + ch * 8;
            f32x4 a = *(const f32x4*)s;
            f32x4 b = *(const f32x4*)(s + 4);
#pragma unroll
            for (int j = 0; j < 4; ++j) {
                vb[j]     = (short)bf16rne(a[j]);
                vb[4 + j] = (short)bf16rne(b[j]);
            }
        } else {
#pragma unroll
            for (int j = 0; j < 8; ++j) vb[j] = 0;
        }
        *(s16x8*)(dst + ch * CST + p * 8) = vb;
    }
}

// ---- ConvLSTM step body: swapped-operand MFMA (z^T = W * X), single pass ----
// r19: setprio bracket REMOVED (single-variable vs r18). The bracket's
// unmodeled side effects fenced the LLVM scheduler per KSTEP -> each wave ran
// {L2-wait, LDS-wait, MFMA} strictly serialized (r18 measured dispatch =
// SUM of the three pipes, 45us model vs 41.8 measured). Unfenced, the
// compiler can hoist next-KSTEP loads above current MFMAs across the huge
// straight-line unrolled bodies (m97: compiler fine-schedules when free).
template<int KW, int CX, int TS, int NS, int XS>
__device__ __forceinline__ void lstm_body(
    unsigned short* __restrict__ smem,
    float* __restrict__ hplane,       // [64][65] f32, dedicated
    const float* __restrict__ xin, long xbstride,
    const float* __restrict__ hin,
    const unsigned short* __restrict__ Bg,
    const float* __restrict__ bias,
    float* __restrict__ c_buf,        // thread-keyed coalesced (internal)
    float* __restrict__ h_out,
    float* __restrict__ y_out, long ybstride,
    int b)
{
    constexpr int PAD = KW / 2;
    constexpr int NP  = TS * TS;
    constexpr int CHX = CX / 8;
    constexpr int CST = NP * 8;              // chunk stride (ushorts)
    constexpr int XPLANE = CHX * CST;

    unsigned short* sx = smem;               // x plane (CHX chunks)
    unsigned short* sh = sx + XPLANE;        // h plane (8 chunks)

    const int tid  = threadIdx.x;
    const int lane = tid & 63, wid = tid >> 6;
    const int ty0 = blockIdx.y * 8, tx0 = blockIdx.x * 8;

    // W fragment stream: wave w owns nfrags {2w, 2w+1} = channels [32w, 32w+32)
    const unsigned short* bq = Bg + (2 * wid) * 512 + lane * 8;

    stage_bf16<CX, TS, PAD, CST>(xin + (long)b * xbstride, sx, ty0, tx0, tid);
    stage_bf16<64, TS, PAD, CST>(hin + (long)b * 4096 * 64, sh, ty0, tx0, tid);
    __syncthreads();

    f32x4 acc[2][4];   // [cf][pf]
#pragma unroll
    for (int cf = 0; cf < 2; ++cf)
#pragma unroll
        for (int pf = 0; pf < 4; ++pf)
#pragma unroll
            for (int q = 0; q < 4; ++q) acc[cf][pf][q] = 0.0f;

    // thread-const X offsets (ushort units). pixel p = pf*16 + (lane&15)
    const int pb  = lane & 15;
    const int kq  = (lane >> 4) * CST;
    const int av0 = (((pb      >> 3) * TS) + (pb      & 7)) * 8 + kq;
    const int av1 = ((((pb+16) >> 3) * TS) + ((pb+16) & 7)) * 8 + kq;
    const int av2 = ((((pb+32) >> 3) * TS) + ((pb+32) & 7)) * 8 + kq;
    const int av3 = ((((pb+48) >> 3) * TS) + ((pb+48) & 7)) * 8 + kq;

    // one k-step: W from L2 (2x16B), X from LDS (4x16B), 8 MFMA.
#define KSTEP(PX, SO)                                                     \
    {                                                                     \
        s16x8 W0 = *(const s16x8*)(bq);                                   \
        s16x8 W1 = *(const s16x8*)(bq + 512);                             \
        s16x8 X0 = *(const s16x8*)((PX) + (SO) + av0);                    \
        s16x8 X1 = *(const s16x8*)((PX) + (SO) + av1);                    \
        s16x8 X2 = *(const s16x8*)((PX) + (SO) + av2);                    \
        s16x8 X3 = *(const s16x8*)((PX) + (SO) + av3);                    \
        acc[0][0] = MFMA16(W0, X0, acc[0][0]);                            \
        acc[1][0] = MFMA16(W1, X0, acc[1][0]);                            \
        acc[0][1] = MFMA16(W0, X1, acc[0][1]);                            \
        acc[1][1] = MFMA16(W1, X1, acc[1][1]);                            \
        acc[0][2] = MFMA16(W0, X2, acc[0][2]);                            \
        acc[1][2] = MFMA16(W1, X2, acc[1][2]);                            \
        acc[0][3] = MFMA16(W0, X3, acc[0][3]);                            \
        acc[1][3] = MFMA16(W1, X3, acc[1][3]);                            \
        bq += 8192;                                                       \
    }

    // ---- x-phase (k-step order matches prep_w) ----
    if (CX == 32) {
#pragma unroll 1
        for (int kh = 0; kh < KW; ++kh) {
#pragma unroll
            for (int kw = 0; kw < KW; ++kw) {
                KSTEP(sx, (kh * TS + kw) * 8);
            }
        }
    } else {
#pragma unroll 1
        for (int kh = 0; kh < KW; ++kh) {
#pragma unroll
            for (int kw = 0; kw < KW; ++kw) {
#pragma unroll
                for (int c2 = 0; c2 < 2; ++c2) {
                    KSTEP(sx, c2 * 4 * CST + (kh * TS + kw) * 8);
                }
            }
        }
    }
    // ---- h-phase (C=64) ----
#pragma unroll 1
    for (int kh = 0; kh < KW; ++kh) {
#pragma unroll
        for (int kw = 0; kw < KW; ++kw) {
#pragma unroll
            for (int c2 = 0; c2 < 2; ++c2) {
                KSTEP(sh, c2 * 4 * CST + (kh * TS + kw) * 8);
            }
        }
    }
#undef KSTEP

    // ---- per-lane gates -> c update (thread-keyed coalesced) + hn to LDS ----
    // Lane holds gates q={i,f,g,o} of feature f = wid*8 + cf*4 + (lane>>4)
    // at pixel p = pf*16 + (lane&15).
    const int pxb  = lane & 15;
    const int fq   = lane >> 4;
    const int tile = blockIdx.y * 8 + blockIdx.x;
    const long cb0 = (((long)b * 64 + tile) * 8) * 512 + tid;
#pragma unroll
    for (int cf = 0; cf < 2; ++cf) {
        const int f = wid * 8 + cf * 4 + fq;
        const float bi  = bias[f];
        const float bfr = bias[64 + f];
        const float bg  = bias[128 + f];
        const float bo  = bias[192 + f];
#pragma unroll
        for (int pf = 0; pf < 4; ++pf) {
            int p   = pf * 16 + pxb;
            long oc = cb0 + (long)(cf * 4 + pf) * 512;   // 512 threads x 4B
            float zi = acc[cf][pf][0] + bi;
            float zf = acc[cf][pf][1] + bfr;
            float zg = acc[cf][pf][2] + bg;
            float zo = acc[cf][pf][3] + bo;
            float cv = c_buf[oc];
            float cn = hsig(zf) * cv + hsig(zi) * tanhf(zg);
            c_buf[oc] = cn;
            hplane[p * 65 + f] = hsig(zo) * tanhf(cn);
        }
    }
    __syncthreads();

    // ---- coalesced h/y write: lane = feature, 256B-contiguous stores ----
    const int f = tid & 63;
#pragma unroll
    for (int j = 0; j < 8; ++j) {
        int p  = (tid >> 6) + j * 8;             // 0..63
        int yy = ty0 + (p >> 3), xx = tx0 + (p & 7);
        int gp = yy * 64 + xx;
        float hn = hplane[p * 65 + f];
        long o = ((long)(b * 64 + yy) * 64 + xx) * 64 + f;
        h_out[o] = hn;
        y_out[(long)b * ybstride + (long)gp * 64 + f] = fmaxf(hn, 0.0f);
    }
}

// ---- fused dual-layer launch: z<4 -> layer1 step t, z>=4 -> layer2 step t-1 ----
// LDS 44.3 KB/block, regs ~40-60 arch + 32 acc <= 128 -> 2 blocks/CU co-resident.
__global__ __launch_bounds__(512, 2)
void lstm_fused(
    const float* __restrict__ x1, const float* __restrict__ h1in,
    const unsigned short* __restrict__ B1g, const float* __restrict__ bias1,
    float* __restrict__ c1, float* __restrict__ h1out, float* __restrict__ y1out,
    const float* __restrict__ x2, const float* __restrict__ h2in,
    const unsigned short* __restrict__ B2g, const float* __restrict__ bias2,
    float* __restrict__ c2, float* __restrict__ h2out, float* __restrict__ y2out,
    int mode)
{
    // L1: (4+8)*1152 = 13824 u16; L2: (8+8)*800 = 12800 u16 -> max 13824
    __shared__ __align__(16) unsigned short smem[13824];
    __shared__ __align__(16) float hplane[64 * 65];
    const int z = blockIdx.z;
    const int b = z & 3;
    const bool doL2 = (mode == 1) || (z >= 4);
    if (!doL2) {
        lstm_body<5, 32, 12, 75, 25>(smem, hplane, x1, (long)8 * 4096 * 32, h1in,
                                     B1g, bias1, c1, h1out,
                                     y1out, (long)8 * 4096 * 64, b);
    } else {
        lstm_body<3, 64, 10, 36, 18>(smem, hplane, x2, (long)8 * 4096 * 64, h2in,
                                     B2g, bias2, c2, h2out,
                                     y2out, (long)8 * 4096 * 64, b);
    }
}

extern "C" void kernel_launch(void* const* d_in, const int* in_sizes, int n_in,
                              void* d_out, int out_size, void* d_ws, size_t ws_size,
                              hipStream_t stream)
{
    const float* x  = (const float*)d_in[0];
    const float* K1 = (const float*)d_in[1];
    const float* R1 = (const float*)d_in[2];
    const float* b1 = (const float*)d_in[3];
    const float* K2 = (const float*)d_in[4];
    const float* R2 = (const float*)d_in[5];
    const float* b2 = (const float*)d_in[6];
    float* out = (float*)d_out;

    const long HW   = 4096;
    const long SZ_S = HW * 64 * 4;      // 1,048,576 floats per [B,H,W,64]
    const long SZ_Y = SZ_S * 8;

    float* ws  = (float*)d_ws;
    float* y1  = ws;                    // 8,388,608 f32 ([B][T][HW][64])
    float* h1a = y1 + SZ_Y;
    float* h1b = h1a + SZ_S;
    float* h2a = h1b + SZ_S;
    float* h2b = h2a + SZ_S;
    float* c1  = h2b + SZ_S;
    float* c2  = c1 + SZ_S;
    unsigned short* B1 = (unsigned short*)(c2 + SZ_S);   // 75*8192 ushorts
    unsigned short* B2 = B1 + (long)75 * 8192;           // 36*8192 ushorts

    // weight prep
    prep_w<25, 32, 75><<<300, 256, 0, stream>>>(K1, R1, B1);
    prep_w<9,  64, 36><<<144, 256, 0, stream>>>(K2, R2, B2);

    hipMemsetAsync(h1a, 0, (size_t)SZ_S * sizeof(float), stream);
    hipMemsetAsync(c1,  0, (size_t)SZ_S * sizeof(float), stream);
    hipMemsetAsync(h2a, 0, (size_t)SZ_S * sizeof(float), stream);
    hipMemsetAsync(c2,  0, (size_t)SZ_S * sizeof(float), stream);

    float* hp1 = h1a; float* hn1 = h1b;
    float* hp2 = h2a; float* hn2 = h2b;

    for (int t = 0; t <= 8; ++t) {
        const int mode = (t == 0) ? 0 : (t == 8) ? 1 : 2;
        const int t1  = (t <= 7) ? t : 7;       // L1 timestep (unused at t=8)
        const int tm1 = (t >= 1) ? t - 1 : 0;   // L2 timestep (unused at t=0)
        dim3 grid(8, 8, mode == 2 ? 8 : 4);
        lstm_fused<<<grid, 512, 0, stream>>>(
            x  + (long)t1 * HW * 32,  hp1, B1, b1, c1, hn1,
            y1 + (long)t1 * HW * 64,
            y1 + (long)tm1 * HW * 64, hp2, B2, b2, c2, hn2,
            out + (long)tm1 * HW * 64,
            mode);
        if (mode != 1) { float* tmp = hp1; hp1 = hn1; hn1 = tmp; }
        if (mode != 0) { float* tmp = hp2; hp2 = hn2; hn2 = tmp; }
    }
}

// Round 20
// 301.881 us; speedup vs baseline: 1.1736x; 1.1736x over previous
//
#include <hip/hip_runtime.h>

typedef __attribute__((ext_vector_type(4))) float f32x4;
typedef __attribute__((ext_vector_type(8))) short s16x8;

#define MFMA16(a, b, c) __builtin_amdgcn_mfma_f32_16x16x32_bf16((a), (b), (c), 0, 0, 0)

__device__ __forceinline__ float hsig(float x) {
    return fminf(fmaxf(0.2f * x + 0.5f, 0.0f), 1.0f);
}

__device__ __forceinline__ unsigned short bf16rne(float v) {
    unsigned u = __float_as_uint(v);
    u += 0x7FFFu + ((u >> 16) & 1u);
    return (unsigned short)(u >> 16);
}

// ---- weight prep: MFMA A-fragment order, GATE-INTERLEAVED rows, bf16 RNE ----
// Bw layout: [ks][ nfrag(16) x lane(64) x 8 ]  (8192 ushorts per ks)
// Row n = output channel in interleaved order c' = 4*feature + gate.
template<int KHW, int CX, int NS>
__global__ __launch_bounds__(256)
void prep_w(const float* __restrict__ Kw, const float* __restrict__ Rw,
            unsigned short* __restrict__ Bw)
{
    int gid = blockIdx.x * 256 + threadIdx.x;
    if (gid >= NS * 1024) return;
    int lane  = gid & 63;
    int nfrag = (gid >> 6) & 15;
    int ks    = gid >> 10;
    int n   = nfrag * 16 + (lane & 15);       // interleaved channel c'
    int src = (n & 3) * 64 + (n >> 2);        // original col: gate*64 + feature
    int kl  = (lane >> 4) * 8;
    constexpr int KX = KHW * CX;
    s16x8 vh;
#pragma unroll
    for (int j = 0; j < 8; ++j) {
        int kg = ks * 32 + kl + j;
        float w = (kg < KX) ? Kw[(long)kg * 256 + src]
                            : Rw[(long)(kg - KX) * 256 + src];
        vh[j] = (short)bf16rne(w);
    }
    unsigned short* o = Bw + (long)ks * 8192 + nfrag * 512 + lane * 8;
    *(s16x8*)o = vh;
}

// ---- stage zero-padded tile as SINGLE bf16 plane (RNE), chunk-major ----
template<int C, int TS, int PAD, int CST>
__device__ __forceinline__ void stage_bf16(const float* __restrict__ gp,
                                           unsigned short* __restrict__ dst,
                                           int ty0, int tx0, int tid)
{
    constexpr int CH = C / 8;
    constexpr int NP = TS * TS;
    for (int i = tid; i < NP * CH; i += 512) {
        int ch = i % CH;
        int p  = i / CH;
        int py = p / TS, px = p % TS;
        int iy = ty0 + py - PAD, ix = tx0 + px - PAD;
        s16x8 vb;
        if (iy >= 0 && iy < 64 && ix >= 0 && ix < 64) {
            const float* s = gp + ((long)(iy * 64 + ix)) * C + ch * 8;
            f32x4 a = *(const f32x4*)s;
            f32x4 b = *(const f32x4*)(s + 4);
#pragma unroll
            for (int j = 0; j < 4; ++j) {
                vb[j]     = (short)bf16rne(a[j]);
                vb[4 + j] = (short)bf16rne(b[j]);
            }
        } else {
#pragma unroll
            for (int j = 0; j < 8; ++j) vb[j] = 0;
        }
        *(s16x8*)(dst + ch * CST + p * 8) = vb;
    }
}

// ---- ConvLSTM step body: swapped-operand MFMA (z^T = W * X), single pass ----
// r20: even/odd W DOUBLE-BUFFER (compile-time parity, no rotation movs).
// r19 showed VGPR stayed 52 -> compiler never hoisted next-kstep W loads;
// each kstep exposed ~200cy L2 latency (pipes summed: 41.8us vs 17.4 max-pipe).
// Forcing Wb[2][2] buffers at source level makes every kstep issue the NEXT
// kstep's W loads before its own MFMAs: ~155cy of MFMA covers the L2 latency.
// Phases fully unrolled so buffer parity folds to constants (rule #20).
template<int KW, int CX, int TS, int NS, int XS>
__device__ __forceinline__ void lstm_body(
    unsigned short* __restrict__ smem,
    float* __restrict__ hplane,       // [64][65] f32, dedicated
    const float* __restrict__ xin, long xbstride,
    const float* __restrict__ hin,
    const unsigned short* __restrict__ Bg,
    const float* __restrict__ bias,
    float* __restrict__ c_buf,        // thread-keyed coalesced (internal)
    float* __restrict__ h_out,
    float* __restrict__ y_out, long ybstride,
    int b)
{
    constexpr int PAD = KW / 2;
    constexpr int NP  = TS * TS;
    constexpr int CHX = CX / 8;
    constexpr int CST = NP * 8;              // chunk stride (ushorts)
    constexpr int XPLANE = CHX * CST;

    unsigned short* sx = smem;               // x plane (CHX chunks)
    unsigned short* sh = sx + XPLANE;        // h plane (8 chunks)

    const int tid  = threadIdx.x;
    const int lane = tid & 63, wid = tid >> 6;
    const int ty0 = blockIdx.y * 8, tx0 = blockIdx.x * 8;

    // W fragment stream: wave w owns nfrags {2w, 2w+1} = channels [32w, 32w+32)
    const unsigned short* bq = Bg + (2 * wid) * 512 + lane * 8;

    // even/odd W buffers; prologue loads ks=0 (parity 0), hides under staging
    s16x8 Wb[2][2];
    Wb[0][0] = *(const s16x8*)(bq);
    Wb[0][1] = *(const s16x8*)(bq + 512);

    stage_bf16<CX, TS, PAD, CST>(xin + (long)b * xbstride, sx, ty0, tx0, tid);
    stage_bf16<64, TS, PAD, CST>(hin + (long)b * 4096 * 64, sh, ty0, tx0, tid);
    __syncthreads();

    f32x4 acc[2][4];   // [cf][pf]
#pragma unroll
    for (int cf = 0; cf < 2; ++cf)
#pragma unroll
        for (int pf = 0; pf < 4; ++pf)
#pragma unroll
            for (int q = 0; q < 4; ++q) acc[cf][pf][q] = 0.0f;

    // thread-const X offsets (ushort units). pixel p = pf*16 + (lane&15)
    const int pb  = lane & 15;
    const int kq  = (lane >> 4) * CST;
    const int av0 = (((pb      >> 3) * TS) + (pb      & 7)) * 8 + kq;
    const int av1 = ((((pb+16) >> 3) * TS) + ((pb+16) & 7)) * 8 + kq;
    const int av2 = ((((pb+32) >> 3) * TS) + ((pb+32) & 7)) * 8 + kq;
    const int av3 = ((((pb+48) >> 3) * TS) + ((pb+48) & 7)) * 8 + kq;

    // one k-step: prefetch NEXT W into Wb[PAR^1], X from LDS, 8 MFMA from
    // Wb[PAR]. PAR is a compile-time constant in the fully-unrolled nests.
#define KSTEP(PX, SO, PAR, PF)                                            \
    {                                                                     \
        if (PF) {                                                         \
            Wb[(PAR) ^ 1][0] = *(const s16x8*)(bq + 8192);                \
            Wb[(PAR) ^ 1][1] = *(const s16x8*)(bq + 8192 + 512);          \
        }                                                                 \
        s16x8 X0 = *(const s16x8*)((PX) + (SO) + av0);                    \
        s16x8 X1 = *(const s16x8*)((PX) + (SO) + av1);                    \
        s16x8 X2 = *(const s16x8*)((PX) + (SO) + av2);                    \
        s16x8 X3 = *(const s16x8*)((PX) + (SO) + av3);                    \
        __builtin_amdgcn_s_setprio(1);                                    \
        acc[0][0] = MFMA16(Wb[PAR][0], X0, acc[0][0]);                    \
        acc[1][0] = MFMA16(Wb[PAR][1], X0, acc[1][0]);                    \
        acc[0][1] = MFMA16(Wb[PAR][0], X1, acc[0][1]);                    \
        acc[1][1] = MFMA16(Wb[PAR][1], X1, acc[1][1]);                    \
        acc[0][2] = MFMA16(Wb[PAR][0], X2, acc[0][2]);                    \
        acc[1][2] = MFMA16(Wb[PAR][1], X2, acc[1][2]);                    \
        acc[0][3] = MFMA16(Wb[PAR][0], X3, acc[0][3]);                    \
        acc[1][3] = MFMA16(Wb[PAR][1], X3, acc[1][3]);                    \
        __builtin_amdgcn_s_setprio(0);                                    \
        bq += 8192;                                                       \
    }

    // ---- x-phase (fully unrolled; parity = global kstep index & 1) ----
    if (CX == 32) {
        // ks = kh*KW + kw
#pragma unroll
        for (int kh = 0; kh < KW; ++kh) {
#pragma unroll
            for (int kw = 0; kw < KW; ++kw) {
                KSTEP(sx, (kh * TS + kw) * 8, ((kh * KW + kw) & 1), 1);
            }
        }
    } else {
        // ks = 2*tap + c2 -> parity = c2
#pragma unroll
        for (int kh = 0; kh < KW; ++kh) {
#pragma unroll
            for (int kw = 0; kw < KW; ++kw) {
#pragma unroll
                for (int c2 = 0; c2 < 2; ++c2) {
                    KSTEP(sx, c2 * 4 * CST + (kh * TS + kw) * 8, (c2 & 1), 1);
                }
            }
        }
    }
    // ---- h-phase: ks = XS + 2*tap + c2 -> parity = (XS + c2) & 1 ----
#pragma unroll
    for (int kh = 0; kh < KW; ++kh) {
#pragma unroll
        for (int kw = 0; kw < KW; ++kw) {
#pragma unroll
            for (int c2 = 0; c2 < 2; ++c2) {
                KSTEP(sh, c2 * 4 * CST + (kh * TS + kw) * 8,
                      ((XS + c2) & 1),
                      !(kh == KW - 1 && kw == KW - 1 && c2 == 1));
            }
        }
    }
#undef KSTEP

    // ---- per-lane gates -> c update (thread-keyed coalesced) + hn to LDS ----
    // Lane holds gates q={i,f,g,o} of feature f = wid*8 + cf*4 + (lane>>4)
    // at pixel p = pf*16 + (lane&15).
    const int pxb  = lane & 15;
    const int fq   = lane >> 4;
    const int tile = blockIdx.y * 8 + blockIdx.x;
    const long cb0 = (((long)b * 64 + tile) * 8) * 512 + tid;
#pragma unroll
    for (int cf = 0; cf < 2; ++cf) {
        const int f = wid * 8 + cf * 4 + fq;
        const float bi  = bias[f];
        const float bfr = bias[64 + f];
        const float bg  = bias[128 + f];
        const float bo  = bias[192 + f];
#pragma unroll
        for (int pf = 0; pf < 4; ++pf) {
            int p   = pf * 16 + pxb;
            long oc = cb0 + (long)(cf * 4 + pf) * 512;   // 512 threads x 4B
            float zi = acc[cf][pf][0] + bi;
            float zf = acc[cf][pf][1] + bfr;
            float zg = acc[cf][pf][2] + bg;
            float zo = acc[cf][pf][3] + bo;
            float cv = c_buf[oc];
            float cn = hsig(zf) * cv + hsig(zi) * tanhf(zg);
            c_buf[oc] = cn;
            hplane[p * 65 + f] = hsig(zo) * tanhf(cn);
        }
    }
    __syncthreads();

    // ---- coalesced h/y write: lane = feature, 256B-contiguous stores ----
    const int f = tid & 63;
#pragma unroll
    for (int j = 0; j < 8; ++j) {
        int p  = (tid >> 6) + j * 8;             // 0..63
        int yy = ty0 + (p >> 3), xx = tx0 + (p & 7);
        int gp = yy * 64 + xx;
        float hn = hplane[p * 65 + f];
        long o = ((long)(b * 64 + yy) * 64 + xx) * 64 + f;
        h_out[o] = hn;
        y_out[(long)b * ybstride + (long)gp * 64 + f] = fmaxf(hn, 0.0f);
    }
}

// ---- fused dual-layer launch: z<4 -> layer1 step t, z>=4 -> layer2 step t-1 ----
// LDS 44.3 KB/block, regs ~85 total (acc 32 + Wb 16 + X 16 + addr) <= 128
// -> 2 blocks/CU co-resident.
__global__ __launch_bounds__(512, 2)
void lstm_fused(
    const float* __restrict__ x1, const float* __restrict__ h1in,
    const unsigned short* __restrict__ B1g, const float* __restrict__ bias1,
    float* __restrict__ c1, float* __restrict__ h1out, float* __restrict__ y1out,
    const float* __restrict__ x2, const float* __restrict__ h2in,
    const unsigned short* __restrict__ B2g, const float* __restrict__ bias2,
    float* __restrict__ c2, float* __restrict__ h2out, float* __restrict__ y2out,
    int mode)
{
    // L1: (4+8)*1152 = 13824 u16; L2: (8+8)*800 = 12800 u16 -> max 13824
    __shared__ __align__(16) unsigned short smem[13824];
    __shared__ __align__(16) float hplane[64 * 65];
    const int z = blockIdx.z;
    const int b = z & 3;
    const bool doL2 = (mode == 1) || (z >= 4);
    if (!doL2) {
        lstm_body<5, 32, 12, 75, 25>(smem, hplane, x1, (long)8 * 4096 * 32, h1in,
                                     B1g, bias1, c1, h1out,
                                     y1out, (long)8 * 4096 * 64, b);
    } else {
        lstm_body<3, 64, 10, 36, 18>(smem, hplane, x2, (long)8 * 4096 * 64, h2in,
                                     B2g, bias2, c2, h2out,
                                     y2out, (long)8 * 4096 * 64, b);
    }
}

extern "C" void kernel_launch(void* const* d_in, const int* in_sizes, int n_in,
                              void* d_out, int out_size, void* d_ws, size_t ws_size,
                              hipStream_t stream)
{
    const float* x  = (const float*)d_in[0];
    const float* K1 = (const float*)d_in[1];
    const float* R1 = (const float*)d_in[2];
    const float* b1 = (const float*)d_in[3];
    const float* K2 = (const float*)d_in[4];
    const float* R2 = (const float*)d_in[5];
    const float* b2 = (const float*)d_in[6];
    float* out = (float*)d_out;

    const long HW   = 4096;
    const long SZ_S = HW * 64 * 4;      // 1,048,576 floats per [B,H,W,64]
    const long SZ_Y = SZ_S * 8;

    float* ws  = (float*)d_ws;
    float* y1  = ws;                    // 8,388,608 f32 ([B][T][HW][64])
    float* h1a = y1 + SZ_Y;
    float* h1b = h1a + SZ_S;
    float* h2a = h1b + SZ_S;
    float* h2b = h2a + SZ_S;
    float* c1  = h2b + SZ_S;
    float* c2  = c1 + SZ_S;
    unsigned short* B1 = (unsigned short*)(c2 + SZ_S);   // 75*8192 ushorts
    unsigned short* B2 = B1 + (long)75 * 8192;           // 36*8192 ushorts

    // weight prep
    prep_w<25, 32, 75><<<300, 256, 0, stream>>>(K1, R1, B1);
    prep_w<9,  64, 36><<<144, 256, 0, stream>>>(K2, R2, B2);

    hipMemsetAsync(h1a, 0, (size_t)SZ_S * sizeof(float), stream);
    hipMemsetAsync(c1,  0, (size_t)SZ_S * sizeof(float), stream);
    hipMemsetAsync(h2a, 0, (size_t)SZ_S * sizeof(float), stream);
    hipMemsetAsync(c2,  0, (size_t)SZ_S * sizeof(float), stream);

    float* hp1 = h1a; float* hn1 = h1b;
    float* hp2 = h2a; float* hn2 = h2b;

    for (int t = 0; t <= 8; ++t) {
        const int mode = (t == 0) ? 0 : (t == 8) ? 1 : 2;
        const int t1  = (t <= 7) ? t : 7;       // L1 timestep (unused at t=8)
        const int tm1 = (t >= 1) ? t - 1 : 0;   // L2 timestep (unused at t=0)
        dim3 grid(8, 8, mode == 2 ? 8 : 4);
        lstm_fused<<<grid, 512, 0, stream>>>(
            x  + (long)t1 * HW * 32,  hp1, B1, b1, c1, hn1,
            y1 + (long)t1 * HW * 64,
            y1 + (long)tm1 * HW * 64, hp2, B2, b2, c2, hn2,
            out + (long)tm1 * HW * 64,
            mode);
        if (mode != 1) { float* tmp = hp1; hp1 = hn1; hn1 = tmp; }
        if (mode != 0) { float* tmp = hp2; hp2 = hn2; hn2 = tmp; }
    }
}

// Round 21
// 289.346 us; speedup vs baseline: 1.2244x; 1.0433x over previous
//
#include <hip/hip_runtime.h>

typedef __attribute__((ext_vector_type(4))) float f32x4;
typedef __attribute__((ext_vector_type(8))) short s16x8;

#define MFMA16(a, b, c) __builtin_amdgcn_mfma_f32_16x16x32_bf16((a), (b), (c), 0, 0, 0)

__device__ __forceinline__ float hsig(float x) {
    return fminf(fmaxf(0.2f * x + 0.5f, 0.0f), 1.0f);
}

__device__ __forceinline__ unsigned short bf16rne(float v) {
    unsigned u = __float_as_uint(v);
    u += 0x7FFFu + ((u >> 16) & 1u);
    return (unsigned short)(u >> 16);
}

// ---- weight prep: MFMA A-fragment order, GATE-INTERLEAVED rows, bf16 RNE ----
// Bw layout: [ks][ nfrag(16) x lane(64) x 8 ]  (8192 ushorts per ks)
// Row n = output channel in interleaved order c' = 4*feature + gate.
template<int KHW, int CX, int NS>
__global__ __launch_bounds__(256)
void prep_w(const float* __restrict__ Kw, const float* __restrict__ Rw,
            unsigned short* __restrict__ Bw)
{
    int gid = blockIdx.x * 256 + threadIdx.x;
    if (gid >= NS * 1024) return;
    int lane  = gid & 63;
    int nfrag = (gid >> 6) & 15;
    int ks    = gid >> 10;
    int n   = nfrag * 16 + (lane & 15);       // interleaved channel c'
    int src = (n & 3) * 64 + (n >> 2);        // original col: gate*64 + feature
    int kl  = (lane >> 4) * 8;
    constexpr int KX = KHW * CX;
    s16x8 vh;
#pragma unroll
    for (int j = 0; j < 8; ++j) {
        int kg = ks * 32 + kl + j;
        float w = (kg < KX) ? Kw[(long)kg * 256 + src]
                            : Rw[(long)(kg - KX) * 256 + src];
        vh[j] = (short)bf16rne(w);
    }
    unsigned short* o = Bw + (long)ks * 8192 + nfrag * 512 + lane * 8;
    *(s16x8*)o = vh;
}

// ---- stage zero-padded tile as SINGLE bf16 plane (RNE), chunk-major ----
// zero=true: write zeros (first-timestep h; replaces the 41us fill kernels).
template<int C, int TS, int PAD, int CST>
__device__ __forceinline__ void stage_bf16(const float* __restrict__ gp,
                                           unsigned short* __restrict__ dst,
                                           int ty0, int tx0, int tid, bool zero)
{
    constexpr int CH = C / 8;
    constexpr int NP = TS * TS;
    for (int i = tid; i < NP * CH; i += 512) {
        int ch = i % CH;
        int p  = i / CH;
        int py = p / TS, px = p % TS;
        int iy = ty0 + py - PAD, ix = tx0 + px - PAD;
        s16x8 vb;
        if (!zero && iy >= 0 && iy < 64 && ix >= 0 && ix < 64) {
            const float* s = gp + ((long)(iy * 64 + ix)) * C + ch * 8;
            f32x4 a = *(const f32x4*)s;
            f32x4 b = *(const f32x4*)(s + 4);
#pragma unroll
            for (int j = 0; j < 4; ++j) {
                vb[j]     = (short)bf16rne(a[j]);
                vb[4 + j] = (short)bf16rne(b[j]);
            }
        } else {
#pragma unroll
            for (int j = 0; j < 8; ++j) vb[j] = 0;
        }
        *(s16x8*)(dst + ch * CST + p * 8) = vb;
    }
}

// ---- compile-time flattened k-step schedule: {h-plane?, lds offset}[NS] ----
template<int KW, int CX, int TS, int NS, int XS>
struct KSched { int so[NS]; int hp[NS]; };

template<int KW, int CX, int TS, int NS, int XS>
constexpr KSched<KW, CX, TS, NS, XS> make_sched() {
    KSched<KW, CX, TS, NS, XS> s{};
    constexpr int CST = TS * TS * 8;
    int i = 0;
    if (CX == 32) {
        for (int kh = 0; kh < KW; ++kh)
            for (int kw = 0; kw < KW; ++kw) {
                s.so[i] = (kh * TS + kw) * 8; s.hp[i] = 0; ++i;
            }
    } else {
        for (int kh = 0; kh < KW; ++kh)
            for (int kw = 0; kw < KW; ++kw)
                for (int c2 = 0; c2 < 2; ++c2) {
                    s.so[i] = c2 * 4 * CST + (kh * TS + kw) * 8; s.hp[i] = 0; ++i;
                }
    }
    for (int kh = 0; kh < KW; ++kh)
        for (int kw = 0; kw < KW; ++kw)
            for (int c2 = 0; c2 < 2; ++c2) {
                s.so[i] = c2 * 4 * CST + (kh * TS + kw) * 8; s.hp[i] = 1; ++i;
            }
    return s;
}

// ---- ConvLSTM step body: swapped-operand MFMA (z^T = W * X), single pass ----
// r21: W AND X even/odd double-buffers over a flattened compile-time k-step
// schedule (full unroll -> all buffer parities and LDS offsets fold to
// constants). Each k-step issues k+1's W (L2) and X (LDS) loads before its
// own 8 MFMAs -> both load latencies hide under the MFMA cluster.
// zi: first-timestep flag -> h staged as zeros, c_buf read skipped.
template<int KW, int CX, int TS, int NS, int XS>
__device__ __forceinline__ void lstm_body(
    unsigned short* __restrict__ smem,
    float* __restrict__ hplane,       // [64][65] f32, dedicated
    const float* __restrict__ xin, long xbstride,
    const float* __restrict__ hin,
    const unsigned short* __restrict__ Bg,
    const float* __restrict__ bias,
    float* __restrict__ c_buf,        // thread-keyed coalesced (internal)
    float* __restrict__ h_out,
    float* __restrict__ y_out, long ybstride,
    int b, bool zi)
{
    constexpr int PAD = KW / 2;
    constexpr int NP  = TS * TS;
    constexpr int CHX = CX / 8;
    constexpr int CST = NP * 8;              // chunk stride (ushorts)
    constexpr int XPLANE = CHX * CST;
    constexpr auto SC = make_sched<KW, CX, TS, NS, XS>();

    unsigned short* sx = smem;               // x plane (CHX chunks)
    unsigned short* sh = sx + XPLANE;        // h plane (8 chunks)

    const int tid  = threadIdx.x;
    const int lane = tid & 63, wid = tid >> 6;
    const int ty0 = blockIdx.y * 8, tx0 = blockIdx.x * 8;

    // W fragment stream: wave w owns nfrags {2w, 2w+1} = channels [32w, 32w+32)
    const unsigned short* bq = Bg + (2 * wid) * 512 + lane * 8;

    // W prologue (ks=0): L2 latency hides under staging + barrier
    s16x8 Wb[2][2];
    Wb[0][0] = *(const s16x8*)(bq);
    Wb[0][1] = *(const s16x8*)(bq + 512);

    stage_bf16<CX, TS, PAD, CST>(xin + (long)b * xbstride, sx, ty0, tx0, tid, false);
    stage_bf16<64, TS, PAD, CST>(hin + (long)b * 4096 * 64, sh, ty0, tx0, tid, zi);
    __syncthreads();

    f32x4 acc[2][4];   // [cf][pf]
#pragma unroll
    for (int cf = 0; cf < 2; ++cf)
#pragma unroll
        for (int pf = 0; pf < 4; ++pf)
#pragma unroll
            for (int q = 0; q < 4; ++q) acc[cf][pf][q] = 0.0f;

    // thread-const X offsets (ushort units). pixel p = pf*16 + (lane&15)
    const int pb  = lane & 15;
    const int kq  = (lane >> 4) * CST;
    const int av0 = (((pb      >> 3) * TS) + (pb      & 7)) * 8 + kq;
    const int av1 = ((((pb+16) >> 3) * TS) + ((pb+16) & 7)) * 8 + kq;
    const int av2 = ((((pb+32) >> 3) * TS) + ((pb+32) & 7)) * 8 + kq;
    const int av3 = ((((pb+48) >> 3) * TS) + ((pb+48) & 7)) * 8 + kq;

    // X prologue (ks=0)
    s16x8 Xb[2][4];
    {
        const unsigned short* pp = SC.hp[0] ? sh : sx;
        Xb[0][0] = *(const s16x8*)(pp + SC.so[0] + av0);
        Xb[0][1] = *(const s16x8*)(pp + SC.so[0] + av1);
        Xb[0][2] = *(const s16x8*)(pp + SC.so[0] + av2);
        Xb[0][3] = *(const s16x8*)(pp + SC.so[0] + av3);
    }

#pragma unroll
    for (int ks = 0; ks < NS; ++ks) {
        if (ks + 1 < NS) {
            // W prefetch for ks+1 (L2)
            Wb[(ks + 1) & 1][0] = *(const s16x8*)(bq + 8192);
            Wb[(ks + 1) & 1][1] = *(const s16x8*)(bq + 8192 + 512);
            // X prefetch for ks+1 (LDS)
            const unsigned short* pp = SC.hp[ks + 1] ? sh : sx;
            Xb[(ks + 1) & 1][0] = *(const s16x8*)(pp + SC.so[ks + 1] + av0);
            Xb[(ks + 1) & 1][1] = *(const s16x8*)(pp + SC.so[ks + 1] + av1);
            Xb[(ks + 1) & 1][2] = *(const s16x8*)(pp + SC.so[ks + 1] + av2);
            Xb[(ks + 1) & 1][3] = *(const s16x8*)(pp + SC.so[ks + 1] + av3);
        }
        __builtin_amdgcn_s_setprio(1);
        acc[0][0] = MFMA16(Wb[ks & 1][0], Xb[ks & 1][0], acc[0][0]);
        acc[1][0] = MFMA16(Wb[ks & 1][1], Xb[ks & 1][0], acc[1][0]);
        acc[0][1] = MFMA16(Wb[ks & 1][0], Xb[ks & 1][1], acc[0][1]);
        acc[1][1] = MFMA16(Wb[ks & 1][1], Xb[ks & 1][1], acc[1][1]);
        acc[0][2] = MFMA16(Wb[ks & 1][0], Xb[ks & 1][2], acc[0][2]);
        acc[1][2] = MFMA16(Wb[ks & 1][1], Xb[ks & 1][2], acc[1][2]);
        acc[0][3] = MFMA16(Wb[ks & 1][0], Xb[ks & 1][3], acc[0][3]);
        acc[1][3] = MFMA16(Wb[ks & 1][1], Xb[ks & 1][3], acc[1][3]);
        __builtin_amdgcn_s_setprio(0);
        bq += 8192;
    }

    // ---- per-lane gates -> c update (thread-keyed coalesced) + hn to LDS ----
    // Lane holds gates q={i,f,g,o} of feature f = wid*8 + cf*4 + (lane>>4)
    // at pixel p = pf*16 + (lane&15).
    const int pxb  = lane & 15;
    const int fq   = lane >> 4;
    const int tile = blockIdx.y * 8 + blockIdx.x;
    const long cb0 = (((long)b * 64 + tile) * 8) * 512 + tid;
#pragma unroll
    for (int cf = 0; cf < 2; ++cf) {
        const int f = wid * 8 + cf * 4 + fq;
        const float bi  = bias[f];
        const float bfr = bias[64 + f];
        const float bg  = bias[128 + f];
        const float bo  = bias[192 + f];
#pragma unroll
        for (int pf = 0; pf < 4; ++pf) {
            int p   = pf * 16 + pxb;
            long oc = cb0 + (long)(cf * 4 + pf) * 512;   // 512 threads x 4B
            float zif = acc[cf][pf][0] + bi;
            float zf  = acc[cf][pf][1] + bfr;
            float zg  = acc[cf][pf][2] + bg;
            float zo  = acc[cf][pf][3] + bo;
            float cv = zi ? 0.0f : c_buf[oc];
            float cn = hsig(zf) * cv + hsig(zif) * tanhf(zg);
            c_buf[oc] = cn;
            hplane[p * 65 + f] = hsig(zo) * tanhf(cn);
        }
    }
    __syncthreads();

    // ---- coalesced h/y write: lane = feature, 256B-contiguous stores ----
    const int f = tid & 63;
#pragma unroll
    for (int j = 0; j < 8; ++j) {
        int p  = (tid >> 6) + j * 8;             // 0..63
        int yy = ty0 + (p >> 3), xx = tx0 + (p & 7);
        int gp = yy * 64 + xx;
        float hn = hplane[p * 65 + f];
        long o = ((long)(b * 64 + yy) * 64 + xx) * 64 + f;
        h_out[o] = hn;
        y_out[(long)b * ybstride + (long)gp * 64 + f] = fmaxf(hn, 0.0f);
    }
}

// ---- fused dual-layer launch: z<4 -> layer1 step t, z>=4 -> layer2 step t-1 ----
// zf bit0: L1 first-step (zero h1/c1); bit1: L2 first-step (zero h2/c2).
// LDS 44.3 KB/block; regs ~110 total (acc 32 + Wb 16 + Xb 32 + addr) <= 128
// -> 2 blocks/CU co-resident.
__global__ __launch_bounds__(512, 2)
void lstm_fused(
    const float* __restrict__ x1, const float* __restrict__ h1in,
    const unsigned short* __restrict__ B1g, const float* __restrict__ bias1,
    float* __restrict__ c1, float* __restrict__ h1out, float* __restrict__ y1out,
    const float* __restrict__ x2, const float* __restrict__ h2in,
    const unsigned short* __restrict__ B2g, const float* __restrict__ bias2,
    float* __restrict__ c2, float* __restrict__ h2out, float* __restrict__ y2out,
    int mode, int zf)
{
    // L1: (4+8)*1152 = 13824 u16; L2: (8+8)*800 = 12800 u16 -> max 13824
    __shared__ __align__(16) unsigned short smem[13824];
    __shared__ __align__(16) float hplane[64 * 65];
    const int z = blockIdx.z;
    const int b = z & 3;
    const bool doL2 = (mode == 1) || (z >= 4);
    if (!doL2) {
        lstm_body<5, 32, 12, 75, 25>(smem, hplane, x1, (long)8 * 4096 * 32, h1in,
                                     B1g, bias1, c1, h1out,
                                     y1out, (long)8 * 4096 * 64, b, (zf & 1) != 0);
    } else {
        lstm_body<3, 64, 10, 36, 18>(smem, hplane, x2, (long)8 * 4096 * 64, h2in,
                                     B2g, bias2, c2, h2out,
                                     y2out, (long)8 * 4096 * 64, b, (zf & 2) != 0);
    }
}

extern "C" void kernel_launch(void* const* d_in, const int* in_sizes, int n_in,
                              void* d_out, int out_size, void* d_ws, size_t ws_size,
                              hipStream_t stream)
{
    const float* x  = (const float*)d_in[0];
    const float* K1 = (const float*)d_in[1];
    const float* R1 = (const float*)d_in[2];
    const float* b1 = (const float*)d_in[3];
    const float* K2 = (const float*)d_in[4];
    const float* R2 = (const float*)d_in[5];
    const float* b2 = (const float*)d_in[6];
    float* out = (float*)d_out;

    const long HW   = 4096;
    const long SZ_S = HW * 64 * 4;      // 1,048,576 floats per [B,H,W,64]
    const long SZ_Y = SZ_S * 8;

    float* ws  = (float*)d_ws;
    float* y1  = ws;                    // 8,388,608 f32 ([B][T][HW][64])
    float* h1a = y1 + SZ_Y;
    float* h1b = h1a + SZ_S;
    float* h2a = h1b + SZ_S;
    float* h2b = h2a + SZ_S;
    float* c1  = h2b + SZ_S;
    float* c2  = c1 + SZ_S;
    unsigned short* B1 = (unsigned short*)(c2 + SZ_S);   // 75*8192 ushorts
    unsigned short* B2 = B1 + (long)75 * 8192;           // 36*8192 ushorts

    // weight prep (no memsets: first-step kernels zero-init h/c themselves)
    prep_w<25, 32, 75><<<300, 256, 0, stream>>>(K1, R1, B1);
    prep_w<9,  64, 36><<<144, 256, 0, stream>>>(K2, R2, B2);

    float* hp1 = h1a; float* hn1 = h1b;
    float* hp2 = h2a; float* hn2 = h2b;

    for (int t = 0; t <= 8; ++t) {
        const int mode = (t == 0) ? 0 : (t == 8) ? 1 : 2;
        const int zf   = (t == 0 ? 1 : 0) | (t == 1 ? 2 : 0);
        const int t1  = (t <= 7) ? t : 7;       // L1 timestep (unused at t=8)
        const int tm1 = (t >= 1) ? t - 1 : 0;   // L2 timestep (unused at t=0)
        dim3 grid(8, 8, mode == 2 ? 8 : 4);
        lstm_fused<<<grid, 512, 0, stream>>>(
            x  + (long)t1 * HW * 32,  hp1, B1, b1, c1, hn1,
            y1 + (long)t1 * HW * 64,
            y1 + (long)tm1 * HW * 64, hp2, B2, b2, c2, hn2,
            out + (long)tm1 * HW * 64,
            mode, zf);
        if (mode != 1) { float* tmp = hp1; hp1 = hn1; hn1 = tmp; }
        if (mode != 0) { float* tmp = hp2; hp2 = hn2; hn2 = tmp; }
    }
}

// Round 22
// 285.908 us; speedup vs baseline: 1.2392x; 1.0120x over previous
//
#include <hip/hip_runtime.h>

typedef __attribute__((ext_vector_type(4))) float f32x4;
typedef __attribute__((ext_vector_type(8))) short s16x8;

#define MFMA16(a, b, c) __builtin_amdgcn_mfma_f32_16x16x32_bf16((a), (b), (c), 0, 0, 0)

__device__ __forceinline__ float hsig(float x) {
    return fminf(fmaxf(0.2f * x + 0.5f, 0.0f), 1.0f);
}

__device__ __forceinline__ unsigned short bf16rne(float v) {
    unsigned u = __float_as_uint(v);
    u += 0x7FFFu + ((u >> 16) & 1u);
    return (unsigned short)(u >> 16);
}

// ---- weight prep: MFMA A-fragment order, GATE-INTERLEAVED rows, bf16 RNE ----
// Bw layout: [ks][ nfrag(16) x lane(64) x 8 ]  (8192 ushorts per ks)
// Row n = output channel in interleaved order c' = 4*feature + gate.
template<int KHW, int CX, int NS>
__global__ __launch_bounds__(256)
void prep_w(const float* __restrict__ Kw, const float* __restrict__ Rw,
            unsigned short* __restrict__ Bw)
{
    int gid = blockIdx.x * 256 + threadIdx.x;
    if (gid >= NS * 1024) return;
    int lane  = gid & 63;
    int nfrag = (gid >> 6) & 15;
    int ks    = gid >> 10;
    int n   = nfrag * 16 + (lane & 15);       // interleaved channel c'
    int src = (n & 3) * 64 + (n >> 2);        // original col: gate*64 + feature
    int kl  = (lane >> 4) * 8;
    constexpr int KX = KHW * CX;
    s16x8 vh;
#pragma unroll
    for (int j = 0; j < 8; ++j) {
        int kg = ks * 32 + kl + j;
        float w = (kg < KX) ? Kw[(long)kg * 256 + src]
                            : Rw[(long)(kg - KX) * 256 + src];
        vh[j] = (short)bf16rne(w);
    }
    unsigned short* o = Bw + (long)ks * 8192 + nfrag * 512 + lane * 8;
    *(s16x8*)o = vh;
}

// ---- stage zero-padded tile as SINGLE bf16 plane (RNE), chunk-major ----
// zero=true: write zeros (first-timestep h; replaces fill kernels).
template<int C, int TS, int PAD, int CST>
__device__ __forceinline__ void stage_bf16(const float* __restrict__ gp,
                                           unsigned short* __restrict__ dst,
                                           int ty0, int tx0, int tid, bool zero)
{
    constexpr int CH = C / 8;
    constexpr int NP = TS * TS;
    for (int i = tid; i < NP * CH; i += 512) {
        int ch = i % CH;
        int p  = i / CH;
        int py = p / TS, px = p % TS;
        int iy = ty0 + py - PAD, ix = tx0 + px - PAD;
        s16x8 vb;
        if (!zero && iy >= 0 && iy < 64 && ix >= 0 && ix < 64) {
            const float* s = gp + ((long)(iy * 64 + ix)) * C + ch * 8;
            f32x4 a = *(const f32x4*)s;
            f32x4 b = *(const f32x4*)(s + 4);
#pragma unroll
            for (int j = 0; j < 4; ++j) {
                vb[j]     = (short)bf16rne(a[j]);
                vb[4 + j] = (short)bf16rne(b[j]);
            }
        } else {
#pragma unroll
            for (int j = 0; j < 8; ++j) vb[j] = 0;
        }
        *(s16x8*)(dst + ch * CST + p * 8) = vb;
    }
}

// ---- compile-time flattened k-step schedule: {h-plane?, lds offset}[NS] ----
template<int KW, int CX, int TS, int NS, int XS>
struct KSched { int so[NS]; int hp[NS]; };

template<int KW, int CX, int TS, int NS, int XS>
constexpr KSched<KW, CX, TS, NS, XS> make_sched() {
    KSched<KW, CX, TS, NS, XS> s{};
    constexpr int CST = TS * TS * 8;
    int i = 0;
    if (CX == 32) {
        for (int kh = 0; kh < KW; ++kh)
            for (int kw = 0; kw < KW; ++kw) {
                s.so[i] = (kh * TS + kw) * 8; s.hp[i] = 0; ++i;
            }
    } else {
        for (int kh = 0; kh < KW; ++kh)
            for (int kw = 0; kw < KW; ++kw)
                for (int c2 = 0; c2 < 2; ++c2) {
                    s.so[i] = c2 * 4 * CST + (kh * TS + kw) * 8; s.hp[i] = 0; ++i;
                }
    }
    for (int kh = 0; kh < KW; ++kh)
        for (int kw = 0; kw < KW; ++kw)
            for (int c2 = 0; c2 < 2; ++c2) {
                s.so[i] = c2 * 4 * CST + (kh * TS + kw) * 8; s.hp[i] = 1; ++i;
            }
    return s;
}

// ---- ConvLSTM step body: swapped-operand MFMA (z^T = W * X), single pass ----
// r22: W prefetch DISTANCE 2 (Wb[3][2], mod-3 static in the full unroll).
// Distance-1 covered only ~155cy of the ~200-225cy L2 latency; distance-2
// gives ~310cy cover -> zero exposed vmcnt per k-step. X stays distance-1
// (LDS ~120cy < 155cy MFMA). zi: first-step flag (zero h, skip c read).
template<int KW, int CX, int TS, int NS, int XS>
__device__ __forceinline__ void lstm_body(
    unsigned short* __restrict__ smem,
    float* __restrict__ hplane,       // [64][65] f32, dedicated
    const float* __restrict__ xin, long xbstride,
    const float* __restrict__ hin,
    const unsigned short* __restrict__ Bg,
    const float* __restrict__ bias,
    float* __restrict__ c_buf,        // thread-keyed coalesced (internal)
    float* __restrict__ h_out,
    float* __restrict__ y_out, long ybstride,
    int b, bool zi)
{
    constexpr int PAD = KW / 2;
    constexpr int NP  = TS * TS;
    constexpr int CHX = CX / 8;
    constexpr int CST = NP * 8;              // chunk stride (ushorts)
    constexpr int XPLANE = CHX * CST;
    constexpr auto SC = make_sched<KW, CX, TS, NS, XS>();

    unsigned short* sx = smem;               // x plane (CHX chunks)
    unsigned short* sh = sx + XPLANE;        // h plane (8 chunks)

    const int tid  = threadIdx.x;
    const int lane = tid & 63, wid = tid >> 6;
    const int ty0 = blockIdx.y * 8, tx0 = blockIdx.x * 8;

    // W fragment stream: wave w owns nfrags {2w, 2w+1} = channels [32w, 32w+32)
    const unsigned short* bq = Bg + (2 * wid) * 512 + lane * 8;

    // W prologue (ks=0,1): L2 latency hides under staging + barrier
    s16x8 Wb[3][2];
    Wb[0][0] = *(const s16x8*)(bq);
    Wb[0][1] = *(const s16x8*)(bq + 512);
    Wb[1][0] = *(const s16x8*)(bq + 8192);
    Wb[1][1] = *(const s16x8*)(bq + 8192 + 512);

    stage_bf16<CX, TS, PAD, CST>(xin + (long)b * xbstride, sx, ty0, tx0, tid, false);
    stage_bf16<64, TS, PAD, CST>(hin + (long)b * 4096 * 64, sh, ty0, tx0, tid, zi);
    __syncthreads();

    f32x4 acc[2][4];   // [cf][pf]
#pragma unroll
    for (int cf = 0; cf < 2; ++cf)
#pragma unroll
        for (int pf = 0; pf < 4; ++pf)
#pragma unroll
            for (int q = 0; q < 4; ++q) acc[cf][pf][q] = 0.0f;

    // thread-const X offsets (ushort units). pixel p = pf*16 + (lane&15)
    const int pb  = lane & 15;
    const int kq  = (lane >> 4) * CST;
    const int av0 = (((pb      >> 3) * TS) + (pb      & 7)) * 8 + kq;
    const int av1 = ((((pb+16) >> 3) * TS) + ((pb+16) & 7)) * 8 + kq;
    const int av2 = ((((pb+32) >> 3) * TS) + ((pb+32) & 7)) * 8 + kq;
    const int av3 = ((((pb+48) >> 3) * TS) + ((pb+48) & 7)) * 8 + kq;

    // X prologue (ks=0)
    s16x8 Xb[2][4];
    {
        const unsigned short* pp = SC.hp[0] ? sh : sx;
        Xb[0][0] = *(const s16x8*)(pp + SC.so[0] + av0);
        Xb[0][1] = *(const s16x8*)(pp + SC.so[0] + av1);
        Xb[0][2] = *(const s16x8*)(pp + SC.so[0] + av2);
        Xb[0][3] = *(const s16x8*)(pp + SC.so[0] + av3);
    }

#pragma unroll
    for (int ks = 0; ks < NS; ++ks) {
        if (ks + 2 < NS) {
            // W prefetch for ks+2 (L2), distance 2
            Wb[(ks + 2) % 3][0] = *(const s16x8*)(bq + 2 * 8192);
            Wb[(ks + 2) % 3][1] = *(const s16x8*)(bq + 2 * 8192 + 512);
        }
        if (ks + 1 < NS) {
            // X prefetch for ks+1 (LDS), distance 1
            const unsigned short* pp = SC.hp[ks + 1] ? sh : sx;
            Xb[(ks + 1) & 1][0] = *(const s16x8*)(pp + SC.so[ks + 1] + av0);
            Xb[(ks + 1) & 1][1] = *(const s16x8*)(pp + SC.so[ks + 1] + av1);
            Xb[(ks + 1) & 1][2] = *(const s16x8*)(pp + SC.so[ks + 1] + av2);
            Xb[(ks + 1) & 1][3] = *(const s16x8*)(pp + SC.so[ks + 1] + av3);
        }
        __builtin_amdgcn_s_setprio(1);
        acc[0][0] = MFMA16(Wb[ks % 3][0], Xb[ks & 1][0], acc[0][0]);
        acc[1][0] = MFMA16(Wb[ks % 3][1], Xb[ks & 1][0], acc[1][0]);
        acc[0][1] = MFMA16(Wb[ks % 3][0], Xb[ks & 1][1], acc[0][1]);
        acc[1][1] = MFMA16(Wb[ks % 3][1], Xb[ks & 1][1], acc[1][1]);
        acc[0][2] = MFMA16(Wb[ks % 3][0], Xb[ks & 1][2], acc[0][2]);
        acc[1][2] = MFMA16(Wb[ks % 3][1], Xb[ks & 1][2], acc[1][2]);
        acc[0][3] = MFMA16(Wb[ks % 3][0], Xb[ks & 1][3], acc[0][3]);
        acc[1][3] = MFMA16(Wb[ks % 3][1], Xb[ks & 1][3], acc[1][3]);
        __builtin_amdgcn_s_setprio(0);
        bq += 8192;
    }

    // ---- per-lane gates -> c update (thread-keyed coalesced) + hn to LDS ----
    // Lane holds gates q={i,f,g,o} of feature f = wid*8 + cf*4 + (lane>>4)
    // at pixel p = pf*16 + (lane&15).
    const int pxb  = lane & 15;
    const int fq   = lane >> 4;
    const int tile = blockIdx.y * 8 + blockIdx.x;
    const long cb0 = (((long)b * 64 + tile) * 8) * 512 + tid;
#pragma unroll
    for (int cf = 0; cf < 2; ++cf) {
        const int f = wid * 8 + cf * 4 + fq;
        const float bi  = bias[f];
        const float bfr = bias[64 + f];
        const float bg  = bias[128 + f];
        const float bo  = bias[192 + f];
#pragma unroll
        for (int pf = 0; pf < 4; ++pf) {
            int p   = pf * 16 + pxb;
            long oc = cb0 + (long)(cf * 4 + pf) * 512;   // 512 threads x 4B
            float zif = acc[cf][pf][0] + bi;
            float zf  = acc[cf][pf][1] + bfr;
            float zg  = acc[cf][pf][2] + bg;
            float zo  = acc[cf][pf][3] + bo;
            float cv = zi ? 0.0f : c_buf[oc];
            float cn = hsig(zf) * cv + hsig(zif) * tanhf(zg);
            c_buf[oc] = cn;
            hplane[p * 65 + f] = hsig(zo) * tanhf(cn);
        }
    }
    __syncthreads();

    // ---- coalesced h/y write: lane = feature, 256B-contiguous stores ----
    const int f = tid & 63;
#pragma unroll
    for (int j = 0; j < 8; ++j) {
        int p  = (tid >> 6) + j * 8;             // 0..63
        int yy = ty0 + (p >> 3), xx = tx0 + (p & 7);
        int gp = yy * 64 + xx;
        float hn = hplane[p * 65 + f];
        long o = ((long)(b * 64 + yy) * 64 + xx) * 64 + f;
        h_out[o] = hn;
        y_out[(long)b * ybstride + (long)gp * 64 + f] = fmaxf(hn, 0.0f);
    }
}

// ---- fused dual-layer launch: z<4 -> layer1 step t, z>=4 -> layer2 step t-1 ----
// zf bit0: L1 first-step (zero h1/c1); bit1: L2 first-step (zero h2/c2).
// LDS 44.3 KB/block; regs ~115 total (acc 32 + Wb 24 + Xb 32 + addr) <= 128
// -> 2 blocks/CU co-resident.
__global__ __launch_bounds__(512, 2)
void lstm_fused(
    const float* __restrict__ x1, const float* __restrict__ h1in,
    const unsigned short* __restrict__ B1g, const float* __restrict__ bias1,
    float* __restrict__ c1, float* __restrict__ h1out, float* __restrict__ y1out,
    const float* __restrict__ x2, const float* __restrict__ h2in,
    const unsigned short* __restrict__ B2g, const float* __restrict__ bias2,
    float* __restrict__ c2, float* __restrict__ h2out, float* __restrict__ y2out,
    int mode, int zf)
{
    // L1: (4+8)*1152 = 13824 u16; L2: (8+8)*800 = 12800 u16 -> max 13824
    __shared__ __align__(16) unsigned short smem[13824];
    __shared__ __align__(16) float hplane[64 * 65];
    const int z = blockIdx.z;
    const int b = z & 3;
    const bool doL2 = (mode == 1) || (z >= 4);
    if (!doL2) {
        lstm_body<5, 32, 12, 75, 25>(smem, hplane, x1, (long)8 * 4096 * 32, h1in,
                                     B1g, bias1, c1, h1out,
                                     y1out, (long)8 * 4096 * 64, b, (zf & 1) != 0);
    } else {
        lstm_body<3, 64, 10, 36, 18>(smem, hplane, x2, (long)8 * 4096 * 64, h2in,
                                     B2g, bias2, c2, h2out,
                                     y2out, (long)8 * 4096 * 64, b, (zf & 2) != 0);
    }
}

extern "C" void kernel_launch(void* const* d_in, const int* in_sizes, int n_in,
                              void* d_out, int out_size, void* d_ws, size_t ws_size,
                              hipStream_t stream)
{
    const float* x  = (const float*)d_in[0];
    const float* K1 = (const float*)d_in[1];
    const float* R1 = (const float*)d_in[2];
    const float* b1 = (const float*)d_in[3];
    const float* K2 = (const float*)d_in[4];
    const float* R2 = (const float*)d_in[5];
    const float* b2 = (const float*)d_in[6];
    float* out = (float*)d_out;

    const long HW   = 4096;
    const long SZ_S = HW * 64 * 4;      // 1,048,576 floats per [B,H,W,64]
    const long SZ_Y = SZ_S * 8;

    float* ws  = (float*)d_ws;
    float* y1  = ws;                    // 8,388,608 f32 ([B][T][HW][64])
    float* h1a = y1 + SZ_Y;
    float* h1b = h1a + SZ_S;
    float* h2a = h1b + SZ_S;
    float* h2b = h2a + SZ_S;
    float* c1  = h2b + SZ_S;
    float* c2  = c1 + SZ_S;
    unsigned short* B1 = (unsigned short*)(c2 + SZ_S);   // 75*8192 ushorts
    unsigned short* B2 = B1 + (long)75 * 8192;           // 36*8192 ushorts

    // weight prep (no memsets: first-step kernels zero-init h/c themselves)
    prep_w<25, 32, 75><<<300, 256, 0, stream>>>(K1, R1, B1);
    prep_w<9,  64, 36><<<144, 256, 0, stream>>>(K2, R2, B2);

    float* hp1 = h1a; float* hn1 = h1b;
    float* hp2 = h2a; float* hn2 = h2b;

    for (int t = 0; t <= 8; ++t) {
        const int mode = (t == 0) ? 0 : (t == 8) ? 1 : 2;
        const int zf   = (t == 0 ? 1 : 0) | (t == 1 ? 2 : 0);
        const int t1  = (t <= 7) ? t : 7;       // L1 timestep (unused at t=8)
        const int tm1 = (t >= 1) ? t - 1 : 0;   // L2 timestep (unused at t=0)
        dim3 grid(8, 8, mode == 2 ? 8 : 4);
        lstm_fused<<<grid, 512, 0, stream>>>(
            x  + (long)t1 * HW * 32,  hp1, B1, b1, c1, hn1,
            y1 + (long)t1 * HW * 64,
            y1 + (long)tm1 * HW * 64, hp2, B2, b2, c2, hn2,
            out + (long)tm1 * HW * 64,
            mode, zf);
        if (mode != 1) { float* tmp = hp1; hp1 = hn1; hn1 = tmp; }
        if (mode != 0) { float* tmp = hp2; hp2 = hn2; hn2 = tmp; }
    }
}